// Round 9
// baseline (149.414 us; speedup 1.0000x reference)
//
#include <hip/hip_runtime.h>

#define B_ 4
#define C_ 256
#define N_ 4096
#define E_ 32

typedef _Float16 f16x8 __attribute__((ext_vector_type(8)));
typedef _Float16 f16x4 __attribute__((ext_vector_type(4)));
typedef float f32x4 __attribute__((ext_vector_type(4)));

#define LOG2E 1.44269504088896f

// ---------------------------------------------------------------------------
// Kernel 1: K/Q/V 1x1-conv projections via f16 MFMA. One matrix per block.
//   Kb[b][n][e] = f, Qb[b][n][e] = g * log2(e), Vb[b][e][n] = h.
// Block 768 (m==3) converts Wo -> f16 workspace copy and writes gamma.
// ---------------------------------------------------------------------------
__global__ __launch_bounds__(256) void proj_kernel(
    const float* __restrict__ x,
    const float* __restrict__ Wk, const float* __restrict__ bk,
    const float* __restrict__ Wq, const float* __restrict__ bq,
    const float* __restrict__ Wv, const float* __restrict__ bv,
    const float* __restrict__ Wo,
    _Float16* __restrict__ Qb, _Float16* __restrict__ Kb, _Float16* __restrict__ Vb,
    _Float16* __restrict__ Wof16, float* __restrict__ out)
{
    const int m = blockIdx.x >> 8;           // 0=K, 1=Q, 2=V, 3=Wo-convert
    if (m == 3) {
        for (int i4 = threadIdx.x; i4 < (C_ * E_) / 4; i4 += 256) {
            float4 wv = ((const float4*)Wo)[i4];
            f16x4 tp = {(_Float16)wv.x, (_Float16)wv.y, (_Float16)wv.z, (_Float16)wv.w};
            *(f16x4*)&Wof16[i4 * 4] = tp;
        }
        if (threadIdx.x == 0)
            out[(size_t)2 * B_ * C_ * N_] = 0.5f;   // gamma (non-learned)
        return;
    }
    const int rem = blockIdx.x & 255;
    const int b   = rem >> 6;
    const int n0  = (rem & 63) << 6;
    const int t    = threadIdx.x;
    const int lane = t & 63;
    const int wave = t >> 6;
    const int l15  = lane & 15;
    const int quad = lane >> 4;

    __shared__ _Float16 xT[64][264];   // x tile transposed: [n_local][c]
    __shared__ _Float16 Wl[32][264];   // this matrix's weights: [e][c]

    const float* W    = (m == 0) ? Wk : (m == 1) ? Wq : Wv;
    const float* bias = (m == 0) ? bk : (m == 1) ? bq : bv;

    for (int i4 = t; i4 < (E_ * C_) / 4; i4 += 256) {
        float4 wv = ((const float4*)W)[i4];
        int e = (i4 * 4) >> 8, c = (i4 * 4) & 255;
        f16x4 tp = {(_Float16)wv.x, (_Float16)wv.y, (_Float16)wv.z, (_Float16)wv.w};
        *(f16x4*)&Wl[e][c] = tp;
    }
    for (int i4 = t; i4 < (64 * 256) / 4; i4 += 256) {
        int j4 = (i4 & 15) * 4;
        int c  = i4 >> 4;
        float4 xv = *(const float4*)(x + (size_t)(b * C_ + c) * N_ + n0 + j4);
        xT[j4 + 0][c] = (_Float16)xv.x;
        xT[j4 + 1][c] = (_Float16)xv.y;
        xT[j4 + 2][c] = (_Float16)xv.z;
        xT[j4 + 3][c] = (_Float16)xv.w;
    }
    __syncthreads();

    f16x8 Bf[8];
    for (int kk = 0; kk < 8; ++kk)
        Bf[kk] = *(const f16x8*)&xT[wave * 16 + l15][kk * 32 + quad * 8];

    const float sc = (m == 1) ? LOG2E : 1.0f;
    for (int et = 0; et < 2; ++et) {
        f32x4 acc = {0.f, 0.f, 0.f, 0.f};
        for (int kk = 0; kk < 8; ++kk) {
            f16x8 Af = *(const f16x8*)&Wl[et * 16 + l15][kk * 32 + quad * 8];
            acc = __builtin_amdgcn_mfma_f32_16x16x32_f16(Af, Bf[kk], acc, 0, 0, 0);
        }
        const int n = n0 + wave * 16 + l15;
        for (int r = 0; r < 4; ++r) {
            const int e = et * 16 + quad * 4 + r;
            float v = (acc[r] + bias[e]) * sc;
            _Float16 hv = (_Float16)v;
            if      (m == 0) Kb[(size_t)(b * N_ + n) * E_ + e] = hv;
            else if (m == 1) Qb[(size_t)(b * N_ + n) * E_ + e] = hv;
            else             Vb[(size_t)(b * E_ + e) * N_ + n] = hv;
        }
    }
}

// ---------------------------------------------------------------------------
// Kernel 2: flash attention + fused output projection.
// R9 change vs R8: osum OVERLAYS pb (barrier-separated phases: all per-wave
// pb reads happen before the first __syncthreads; all osum writes after it).
// LDS 53.8 -> 35.1 KB => 4 blocks/CU x 8 waves = 32 waves/CU (R8 was stuck
// at 2 blocks/CU: the 2.5 KB margin at 53.8 KB was below alloc granularity).
// ---------------------------------------------------------------------------
__global__ __launch_bounds__(512, 4) void attn_kernel(
    const _Float16* __restrict__ Qb, const _Float16* __restrict__ Kb,
    const _Float16* __restrict__ Vb, const _Float16* __restrict__ Wof16,
    const float* __restrict__ bo, const float* __restrict__ x,
    float* __restrict__ out)
{
    const int wave = threadIdx.x >> 6;     // i-split 0..7
    const int lane = threadIdx.x & 63;
    const int l15  = lane & 15, quad = lane >> 4;
    const int jg   = blockIdx.x;           // 0..1023
    const int b    = jg >> 8;
    const int j0   = (jg & 255) << 4;

    // per-wave 4224 B region: phase 1 = pb [16][132] f16; phase 2 = osum
    // [16][34] f32 (2176 B) overlay. Phases separated by __syncthreads.
    __shared__ __align__(16) char pbuf[8][4224];
    __shared__ float    mls[8][2][16];     // per-wave (m, l) per j
    __shared__ _Float16 Om[16][36];        // merged O rows (f16) for out-proj

    _Float16 (*pb)[132] = (_Float16 (*)[132])(pbuf[wave]);

    // Q B-frag: B[k=e][n=j], lane j=l15, k=quad*8.. from Qb[j][e]
    f16x8 Qf = *(const f16x8*)(Qb + (size_t)(b * N_ + j0 + l15) * E_ + quad * 8);

    f32x4 O0 = {0, 0, 0, 0}, O1 = {0, 0, 0, 0};   // O^T[e][j]
    float mrow = -1e30f, lsum = 0.f;               // per-lane (per-j) state

    const _Float16* Kbase = Kb + (size_t)b * N_ * E_;
    const _Float16* Vbase = Vb + (size_t)b * E_ * N_;
    const int ibase = wave << 9;           // split * 512

    // preload K tile 0 (8 x b128)
    f16x8 Kf[8];
    for (int s = 0; s < 8; ++s)
        Kf[s] = *(const f16x8*)(Kbase + (size_t)(ibase + s * 16 + l15) * E_ + quad * 8);

    for (int it = 0; it < 4; ++it) {
        const int i0 = ibase + it * 128;
        // S^T tiles: D[i][j], A=K (m=i), B=Q (n=j)
        f32x4 S[8];
        for (int s = 0; s < 8; ++s) {
            f32x4 z = {0, 0, 0, 0};
            S[s] = __builtin_amdgcn_mfma_f32_16x16x32_f16(Kf[s], Qf, z, 0, 0, 0);
        }
        // max over i: pairwise tree + 2 quad shfls
        float t0, t1, t2, t3;
        t0 = fmaxf(fmaxf(S[0][0], S[0][1]), fmaxf(S[0][2], S[0][3]));
        t1 = fmaxf(fmaxf(S[1][0], S[1][1]), fmaxf(S[1][2], S[1][3]));
        t2 = fmaxf(fmaxf(S[2][0], S[2][1]), fmaxf(S[2][2], S[2][3]));
        t3 = fmaxf(fmaxf(S[3][0], S[3][1]), fmaxf(S[3][2], S[3][3]));
        float mA = fmaxf(fmaxf(t0, t1), fmaxf(t2, t3));
        t0 = fmaxf(fmaxf(S[4][0], S[4][1]), fmaxf(S[4][2], S[4][3]));
        t1 = fmaxf(fmaxf(S[5][0], S[5][1]), fmaxf(S[5][2], S[5][3]));
        t2 = fmaxf(fmaxf(S[6][0], S[6][1]), fmaxf(S[6][2], S[6][3]));
        t3 = fmaxf(fmaxf(S[7][0], S[7][1]), fmaxf(S[7][2], S[7][3]));
        float mx = fmaxf(mA, fmaxf(fmaxf(t0, t1), fmaxf(t2, t3)));
        mx = fmaxf(mx, __shfl_xor(mx, 16));
        mx = fmaxf(mx, __shfl_xor(mx, 32));
        float mnew  = fmaxf(mrow, mx);
        float alpha = exp2f(mrow - mnew);          // log2 domain
        mrow = mnew;
        // exps (independent) + pairwise partial sums
        float ss[8];
        for (int s = 0; s < 8; ++s) {
            float p0 = exp2f(S[s][0] - mnew);
            float p1 = exp2f(S[s][1] - mnew);
            float p2 = exp2f(S[s][2] - mnew);
            float p3 = exp2f(S[s][3] - mnew);
            S[s][0] = p0; S[s][1] = p1; S[s][2] = p2; S[s][3] = p3;
            ss[s] = (p0 + p1) + (p2 + p3);
        }
        float ps = ((ss[0] + ss[1]) + (ss[2] + ss[3]))
                 + ((ss[4] + ss[5]) + (ss[6] + ss[7]));
        lsum = lsum * alpha + ps;
        for (int r = 0; r < 4; ++r) { O0[r] *= alpha; O1[r] *= alpha; }
        // P^T (D-layout) -> B-frag layout: packed b64 writes; compiler
        // inserts the precise lgkmcnt wait for the aliasing reads below.
        for (int s = 0; s < 8; ++s) {
            f16x4 tp = {(_Float16)S[s][0], (_Float16)S[s][1],
                        (_Float16)S[s][2], (_Float16)S[s][3]};
            *(f16x4*)&pb[l15][s * 16 + quad * 4] = tp;
        }
        f16x8 P[4];
        for (int kc = 0; kc < 4; ++kc)
            P[kc] = *(const f16x8*)&pb[l15][kc * 32 + quad * 8];
        // V(cur) + K(next) loads — compiler-scheduled under the MFMAs
        f16x8 Va[4], Vc[4];
        for (int kc = 0; kc < 4; ++kc) {
            Va[kc] = *(const f16x8*)(Vbase + (size_t)l15 * N_ + i0 + kc * 32 + quad * 8);
            Vc[kc] = *(const f16x8*)(Vbase + (size_t)(16 + l15) * N_ + i0 + kc * 32 + quad * 8);
        }
        const int inext = (it < 3) ? (i0 + 128) : ibase;   // clamp (dummy last)
        for (int s = 0; s < 8; ++s)
            Kf[s] = *(const f16x8*)(Kbase + (size_t)(inext + s * 16 + l15) * E_ + quad * 8);
        // PV: O^T += V x P
        for (int kc = 0; kc < 4; ++kc) {
            O0 = __builtin_amdgcn_mfma_f32_16x16x32_f16(Va[kc], P[kc], O0, 0, 0, 0);
            O1 = __builtin_amdgcn_mfma_f32_16x16x32_f16(Vc[kc], P[kc], O1, 0, 0, 0);
        }
    }

    // finish per-split l (sum over quads), publish (m, l)
    lsum += __shfl_xor(lsum, 16);
    lsum += __shfl_xor(lsum, 32);
    if (quad == 0) { mls[wave][0][l15] = mrow; mls[wave][1][l15] = lsum; }
    __syncthreads();   // <- all pb reads complete before this barrier

    // log-sum-exp combine weights across 8 splits (redundant per quad)
    float M = -1e30f, ms[8], ls[8];
    for (int s = 0; s < 8; ++s) {
        ms[s] = mls[s][0][l15]; ls[s] = mls[s][1][l15];
        M = fmaxf(M, ms[s]);
    }
    float L = 0.f;
    for (int s = 0; s < 8; ++s) L += ls[s] * exp2f(ms[s] - M);
    const float w = exp2f(mrow - M) / L;

    // osum overlays pb (phase 2)
    float (*osum)[34] = (float (*)[34])(pbuf[wave]);
    *(f32x4*)&osum[l15][quad * 4]      = O0 * w;
    *(f32x4*)&osum[l15][16 + quad * 4] = O1 * w;
    __syncthreads();

    // cross-split sum -> merged O row (f16) in LDS; one thread per (j, e)
    {
        const int j = threadIdx.x >> 5;    // 0..15
        const int e = threadIdx.x & 31;    // 0..31
        float a = 0.f;
        for (int s = 0; s < 8; ++s)
            a += ((const float (*)[34])(pbuf[s]))[j][e];
        Om[j][e] = (_Float16)a;
    }
    __syncthreads();

    // ---- fused output projection: each wave covers 32 channels ----
    // B[k=e][n=j] from Om; A[m=c][k=e] from L2-resident Wof16.
    f16x8 Bf2 = *(const f16x8*)&Om[l15][quad * 8];
    float* out_y = out + (size_t)b * C_ * N_;
    float* out_o = out + (size_t)B_ * C_ * N_ + (size_t)b * C_ * N_;
    const float* xb = x + (size_t)b * C_ * N_;
    for (int ct = 0; ct < 2; ++ct) {
        const int c0 = wave * 32 + ct * 16;
        f16x8 Af = *(const f16x8*)(Wof16 + (size_t)(c0 + l15) * E_ + quad * 8);
        f32x4 z = {0, 0, 0, 0};
        f32x4 acc = __builtin_amdgcn_mfma_f32_16x16x32_f16(Af, Bf2, z, 0, 0, 0);
        for (int r = 0; r < 4; ++r) {
            const int c = c0 + quad * 4 + r;
            size_t idx = (size_t)c * N_ + j0 + l15;
            float ov = acc[r] + bo[c];
            out_o[idx] = ov;
            out_y[idx] = 0.5f * ov + xb[idx];
        }
    }
}

// ---------------------------------------------------------------------------
extern "C" void kernel_launch(void* const* d_in, const int* in_sizes, int n_in,
                              void* d_out, int out_size, void* d_ws, size_t ws_size,
                              hipStream_t stream)
{
    const float* x  = (const float*)d_in[0];
    const float* Wk = (const float*)d_in[1];
    const float* bk = (const float*)d_in[2];
    const float* Wq = (const float*)d_in[3];
    const float* bq = (const float*)d_in[4];
    const float* Wv = (const float*)d_in[5];
    const float* bv = (const float*)d_in[6];
    const float* Wo = (const float*)d_in[7];
    const float* bo = (const float*)d_in[8];
    float* out = (float*)d_out;

    char* ws = (char*)d_ws;
    _Float16* Qb    = (_Float16*)(ws);                   // 1 MB  [B][N][E]
    _Float16* Kb    = (_Float16*)(ws + (1u << 20));      // 1 MB  [B][N][E]
    _Float16* Vb    = (_Float16*)(ws + (2u << 20));      // 1 MB  [B][E][N]
    _Float16* Wof16 = (_Float16*)(ws + (3u << 20));      // 16 KB [C][E]

    proj_kernel<<<dim3(3 * B_ * (N_ / 64) + 256), dim3(256), 0, stream>>>(
        x, Wk, bk, Wq, bq, Wv, bv, Wo, Qb, Kb, Vb, Wof16, out);
    attn_kernel<<<dim3(B_ * (N_ / 16)), dim3(512), 0, stream>>>(
        Qb, Kb, Vb, Wof16, bo, x, out);
}

// Round 10
// 148.686 us; speedup vs baseline: 1.0049x; 1.0049x over previous
//
#include <hip/hip_runtime.h>

#define B_ 4
#define C_ 256
#define N_ 4096
#define E_ 32

typedef _Float16 f16x8 __attribute__((ext_vector_type(8)));
typedef _Float16 f16x4 __attribute__((ext_vector_type(4)));
typedef float f32x4 __attribute__((ext_vector_type(4)));

#define LOG2E 1.44269504088896f

// ---------------------------------------------------------------------------
// Kernel 1: K/Q/V 1x1-conv projections via f16 MFMA. One matrix per block.
//   Kb[b][n][e] = f, Qb[b][n][e] = g * log2(e), Vb[b][e][n] = h.
// Block 768 (m==3) converts Wo -> f16 workspace copy and writes gamma.
// ---------------------------------------------------------------------------
__global__ __launch_bounds__(256) void proj_kernel(
    const float* __restrict__ x,
    const float* __restrict__ Wk, const float* __restrict__ bk,
    const float* __restrict__ Wq, const float* __restrict__ bq,
    const float* __restrict__ Wv, const float* __restrict__ bv,
    const float* __restrict__ Wo,
    _Float16* __restrict__ Qb, _Float16* __restrict__ Kb, _Float16* __restrict__ Vb,
    _Float16* __restrict__ Wof16, float* __restrict__ out)
{
    const int m = blockIdx.x >> 8;           // 0=K, 1=Q, 2=V, 3=Wo-convert
    if (m == 3) {
        for (int i4 = threadIdx.x; i4 < (C_ * E_) / 4; i4 += 256) {
            float4 wv = ((const float4*)Wo)[i4];
            f16x4 tp = {(_Float16)wv.x, (_Float16)wv.y, (_Float16)wv.z, (_Float16)wv.w};
            *(f16x4*)&Wof16[i4 * 4] = tp;
        }
        if (threadIdx.x == 0)
            out[(size_t)2 * B_ * C_ * N_] = 0.5f;   // gamma (non-learned)
        return;
    }
    const int rem = blockIdx.x & 255;
    const int b   = rem >> 6;
    const int n0  = (rem & 63) << 6;
    const int t    = threadIdx.x;
    const int lane = t & 63;
    const int wave = t >> 6;
    const int l15  = lane & 15;
    const int quad = lane >> 4;

    __shared__ _Float16 xT[64][264];   // x tile transposed: [n_local][c]
    __shared__ _Float16 Wl[32][264];   // this matrix's weights: [e][c]

    const float* W    = (m == 0) ? Wk : (m == 1) ? Wq : Wv;
    const float* bias = (m == 0) ? bk : (m == 1) ? bq : bv;

    for (int i4 = t; i4 < (E_ * C_) / 4; i4 += 256) {
        float4 wv = ((const float4*)W)[i4];
        int e = (i4 * 4) >> 8, c = (i4 * 4) & 255;
        f16x4 tp = {(_Float16)wv.x, (_Float16)wv.y, (_Float16)wv.z, (_Float16)wv.w};
        *(f16x4*)&Wl[e][c] = tp;
    }
    for (int i4 = t; i4 < (64 * 256) / 4; i4 += 256) {
        int j4 = (i4 & 15) * 4;
        int c  = i4 >> 4;
        float4 xv = *(const float4*)(x + (size_t)(b * C_ + c) * N_ + n0 + j4);
        xT[j4 + 0][c] = (_Float16)xv.x;
        xT[j4 + 1][c] = (_Float16)xv.y;
        xT[j4 + 2][c] = (_Float16)xv.z;
        xT[j4 + 3][c] = (_Float16)xv.w;
    }
    __syncthreads();

    f16x8 Bf[8];
    for (int kk = 0; kk < 8; ++kk)
        Bf[kk] = *(const f16x8*)&xT[wave * 16 + l15][kk * 32 + quad * 8];

    const float sc = (m == 1) ? LOG2E : 1.0f;
    for (int et = 0; et < 2; ++et) {
        f32x4 acc = {0.f, 0.f, 0.f, 0.f};
        for (int kk = 0; kk < 8; ++kk) {
            f16x8 Af = *(const f16x8*)&Wl[et * 16 + l15][kk * 32 + quad * 8];
            acc = __builtin_amdgcn_mfma_f32_16x16x32_f16(Af, Bf[kk], acc, 0, 0, 0);
        }
        const int n = n0 + wave * 16 + l15;
        for (int r = 0; r < 4; ++r) {
            const int e = et * 16 + quad * 4 + r;
            float v = (acc[r] + bias[e]) * sc;
            _Float16 hv = (_Float16)v;
            if      (m == 0) Kb[(size_t)(b * N_ + n) * E_ + e] = hv;
            else if (m == 1) Qb[(size_t)(b * N_ + n) * E_ + e] = hv;
            else             Vb[(size_t)(b * E_ + e) * N_ + n] = hv;
        }
    }
}

// ---------------------------------------------------------------------------
// Kernel 2: flash attention + fused output projection.
// R10 change vs R9: REGISTER diet. R6 control-experiment showed occupancy
// follows total (VGPR+AGPR unified) regs: 56 VGPR + ~56 acc regs = ~112/wave
// -> 4 waves/SIMD cap, which LDS trims couldn't move. Now: 32-key tiles
// (S[2], Kf[2], P x1, V x2), just-in-time loads, NO prefetch arrays ->
// live set ~64 regs -> 6-8 waves/SIMD. launch_bounds(512,6) caps at 85
// (insurance, still well above live set -> no spill).
// ---------------------------------------------------------------------------
__global__ __launch_bounds__(512, 6) void attn_kernel(
    const _Float16* __restrict__ Qb, const _Float16* __restrict__ Kb,
    const _Float16* __restrict__ Vb, const _Float16* __restrict__ Wof16,
    const float* __restrict__ bo, const float* __restrict__ x,
    float* __restrict__ out)
{
    const int wave = threadIdx.x >> 6;     // i-split 0..7
    const int lane = threadIdx.x & 63;
    const int l15  = lane & 15, quad = lane >> 4;
    const int jg   = blockIdx.x;           // 0..1023
    const int b    = jg >> 8;
    const int j0   = (jg & 255) << 4;

    // per-wave 2176 B region: phase 1 = pb [16][40] f16 (1280 B);
    // phase 2 = osum [16][34] f32 (2176 B) overlay (barrier-separated).
    __shared__ __align__(16) char pbuf[8][2176];
    __shared__ float    mls[8][2][16];     // per-wave (m, l) per j
    __shared__ _Float16 Om[16][40];        // merged O rows (f16), b128 rows

    _Float16 (*pb)[40] = (_Float16 (*)[40])(pbuf[wave]);

    // Q B-frag: B[k=e][n=j], lane j=l15, k=quad*8.. from Qb[j][e]
    f16x8 Qf = *(const f16x8*)(Qb + (size_t)(b * N_ + j0 + l15) * E_ + quad * 8);

    f32x4 O0 = {0, 0, 0, 0}, O1 = {0, 0, 0, 0};   // O^T[e][j]
    float mrow = -1e30f, lsum = 0.f;               // per-lane (per-j) state

    const _Float16* Kp  = Kb + (size_t)b * N_ * E_ + (size_t)(wave << 9) * E_;
    const _Float16* Vp  = Vb + (size_t)b * E_ * N_ + (wave << 9);

    for (int it = 0; it < 16; ++it) {
        const int i0 = it * 32;
        // K A-frags for 2 16-row tiles (just-in-time; TLP hides latency)
        f16x8 K0 = *(const f16x8*)(Kp + (size_t)(i0 + l15) * E_ + quad * 8);
        f16x8 K1 = *(const f16x8*)(Kp + (size_t)(i0 + 16 + l15) * E_ + quad * 8);
        // V A-frags (independent of softmax; issue early)
        f16x8 Va = *(const f16x8*)(Vp + (size_t)l15 * N_ + i0 + quad * 8);
        f16x8 Vc = *(const f16x8*)(Vp + (size_t)(16 + l15) * N_ + i0 + quad * 8);
        f32x4 z = {0, 0, 0, 0};
        f32x4 S0 = __builtin_amdgcn_mfma_f32_16x16x32_f16(K0, Qf, z, 0, 0, 0);
        f32x4 S1 = __builtin_amdgcn_mfma_f32_16x16x32_f16(K1, Qf, z, 0, 0, 0);
        // max over the 8 in-lane scores + 2 quad shfls
        float a0 = fmaxf(S0[0], S0[1]), a1 = fmaxf(S0[2], S0[3]);
        float a2 = fmaxf(S1[0], S1[1]), a3 = fmaxf(S1[2], S1[3]);
        float mx = fmaxf(fmaxf(a0, a1), fmaxf(a2, a3));
        mx = fmaxf(mx, __shfl_xor(mx, 16));
        mx = fmaxf(mx, __shfl_xor(mx, 32));
        float mnew  = fmaxf(mrow, mx);
        float alpha = exp2f(mrow - mnew);          // log2 domain
        mrow = mnew;
        float p00 = exp2f(S0[0] - mnew), p01 = exp2f(S0[1] - mnew);
        float p02 = exp2f(S0[2] - mnew), p03 = exp2f(S0[3] - mnew);
        float p10 = exp2f(S1[0] - mnew), p11 = exp2f(S1[1] - mnew);
        float p12 = exp2f(S1[2] - mnew), p13 = exp2f(S1[3] - mnew);
        float ps = ((p00 + p01) + (p02 + p03)) + ((p10 + p11) + (p12 + p13));
        lsum = lsum * alpha + ps;
        for (int r = 0; r < 4; ++r) { O0[r] *= alpha; O1[r] *= alpha; }
        // P^T (D-layout) -> B-frag layout via per-wave LDS (2 x b64 write,
        // 1 x b128 read; compiler inserts the precise lgkmcnt)
        f16x4 w0 = {(_Float16)p00, (_Float16)p01, (_Float16)p02, (_Float16)p03};
        f16x4 w1 = {(_Float16)p10, (_Float16)p11, (_Float16)p12, (_Float16)p13};
        *(f16x4*)&pb[l15][quad * 4]      = w0;
        *(f16x4*)&pb[l15][16 + quad * 4] = w1;
        f16x8 P = *(const f16x8*)&pb[l15][quad * 8];
        // PV: O^T += V x P
        O0 = __builtin_amdgcn_mfma_f32_16x16x32_f16(Va, P, O0, 0, 0, 0);
        O1 = __builtin_amdgcn_mfma_f32_16x16x32_f16(Vc, P, O1, 0, 0, 0);
    }

    // finish per-split l (sum over quads), publish (m, l)
    lsum += __shfl_xor(lsum, 16);
    lsum += __shfl_xor(lsum, 32);
    if (quad == 0) { mls[wave][0][l15] = mrow; mls[wave][1][l15] = lsum; }
    __syncthreads();   // <- all pb reads complete before this barrier

    // log-sum-exp combine weights across 8 splits (redundant per quad)
    float M = -1e30f, ms[8], ls[8];
    for (int s = 0; s < 8; ++s) {
        ms[s] = mls[s][0][l15]; ls[s] = mls[s][1][l15];
        M = fmaxf(M, ms[s]);
    }
    float L = 0.f;
    for (int s = 0; s < 8; ++s) L += ls[s] * exp2f(ms[s] - M);
    const float w = exp2f(mrow - M) / L;

    // osum overlays pb (phase 2)
    float (*osum)[34] = (float (*)[34])(pbuf[wave]);
    *(f32x4*)&osum[l15][quad * 4]      = O0 * w;
    *(f32x4*)&osum[l15][16 + quad * 4] = O1 * w;
    __syncthreads();

    // cross-split sum -> merged O row (f16) in LDS; one thread per (j, e)
    {
        const int j = threadIdx.x >> 5;    // 0..15
        const int e = threadIdx.x & 31;    // 0..31
        float a = 0.f;
        for (int s = 0; s < 8; ++s)
            a += ((const float (*)[34])(pbuf[s]))[j][e];
        Om[j][e] = (_Float16)a;
    }
    __syncthreads();

    // ---- fused output projection: each wave covers 32 channels ----
    // B[k=e][n=j] from Om; A[m=c][k=e] from L2-resident Wof16.
    f16x8 Bf2 = *(const f16x8*)&Om[l15][quad * 8];
    float* out_y = out + (size_t)b * C_ * N_;
    float* out_o = out + (size_t)B_ * C_ * N_ + (size_t)b * C_ * N_;
    const float* xb = x + (size_t)b * C_ * N_;
    for (int ct = 0; ct < 2; ++ct) {
        const int c0 = wave * 32 + ct * 16;
        f16x8 Af = *(const f16x8*)(Wof16 + (size_t)(c0 + l15) * E_ + quad * 8);
        f32x4 z = {0, 0, 0, 0};
        f32x4 acc = __builtin_amdgcn_mfma_f32_16x16x32_f16(Af, Bf2, z, 0, 0, 0);
        for (int r = 0; r < 4; ++r) {
            const int c = c0 + quad * 4 + r;
            size_t idx = (size_t)c * N_ + j0 + l15;
            float ov = acc[r] + bo[c];
            out_o[idx] = ov;
            out_y[idx] = 0.5f * ov + xb[idx];
        }
    }
}

// ---------------------------------------------------------------------------
extern "C" void kernel_launch(void* const* d_in, const int* in_sizes, int n_in,
                              void* d_out, int out_size, void* d_ws, size_t ws_size,
                              hipStream_t stream)
{
    const float* x  = (const float*)d_in[0];
    const float* Wk = (const float*)d_in[1];
    const float* bk = (const float*)d_in[2];
    const float* Wq = (const float*)d_in[3];
    const float* bq = (const float*)d_in[4];
    const float* Wv = (const float*)d_in[5];
    const float* bv = (const float*)d_in[6];
    const float* Wo = (const float*)d_in[7];
    const float* bo = (const float*)d_in[8];
    float* out = (float*)d_out;

    char* ws = (char*)d_ws;
    _Float16* Qb    = (_Float16*)(ws);                   // 1 MB  [B][N][E]
    _Float16* Kb    = (_Float16*)(ws + (1u << 20));      // 1 MB  [B][N][E]
    _Float16* Vb    = (_Float16*)(ws + (2u << 20));      // 1 MB  [B][E][N]
    _Float16* Wof16 = (_Float16*)(ws + (3u << 20));      // 16 KB [C][E]

    proj_kernel<<<dim3(3 * B_ * (N_ / 64) + 256), dim3(256), 0, stream>>>(
        x, Wk, bk, Wq, bq, Wv, bv, Wo, Qb, Kb, Vb, Wof16, out);
    attn_kernel<<<dim3(B_ * (N_ / 16)), dim3(512), 0, stream>>>(
        Qb, Kb, Vb, Wof16, bo, x, out);
}